// Round 3
// baseline (589.480 us; speedup 1.0000x reference)
//
#include <hip/hip_runtime.h>
#include <hip/hip_bf16.h>

#define N_NODES 100000
#define N_EDGES 1000000
#define EMB 64
#define HID 64
#define VOCAB 128
#define N_GRAPHS 2048

#define CBUCKET 256                                    // nodes per bucket
#define NBK ((N_NODES + CBUCKET - 1) / CBUCKET)        // 391
#define CAP 4096                                       // slots per bucket (E[cnt]=2560, 30 sigma)
#define CHUNK 4096
#define SCAT_BLOCKS ((N_EDGES + CHUNK - 1) / CHUNK)    // 245
#define GB ((N_NODES + 255) / 256)                     // 391 gstart blocks

#define BCASTF(v, l) __int_as_float(__builtin_amdgcn_readlane(__float_as_int(v), (l)))

typedef __attribute__((ext_vector_type(8))) short short8;
typedef __attribute__((ext_vector_type(4))) float f32x4;
typedef __attribute__((ext_vector_type(2))) float f32x2;

__device__ __forceinline__ float bf2f(unsigned short u) {
    return __uint_as_float((unsigned)u << 16);
}
__device__ __forceinline__ unsigned short f2bf(float f) {
    return __bfloat16_as_ushort(__float2bfloat16(f));
}

// ---- merged scatter + setup: blocks [0,245) scatter, [245,636) gstart,
//      [636,668) precompute. cursor/gsum pre-zeroed by one memset.
__global__ __launch_bounds__(256) void scatter_kernel(
    const int* __restrict__ src, const int* __restrict__ dst,
    const int* __restrict__ x,
    int* __restrict__ cursor, unsigned* __restrict__ edge8,
    const int* __restrict__ batch, int* __restrict__ gstart,
    const float* __restrict__ emb, const float* __restrict__ W1l,
    const float* __restrict__ W1r,
    const float* __restrict__ W2l, const float* __restrict__ W2r,
    float* __restrict__ embW1l, float* __restrict__ embW1r,
    unsigned short* __restrict__ w2frag, unsigned char* __restrict__ p8z)
{
    __shared__ unsigned earr[CHUNK];            // 16 KB packed payload
    __shared__ unsigned short karr[CHUNK];      // 8 KB bucket key (0..390)
    __shared__ int bcnt[NBK];
    __shared__ int bbase[NBK];
    int b = blockIdx.x;
    int t = threadIdx.x;

    if (b < SCAT_BLOCKS) {
        // ---- scatter: LDS-staged chunk, per-(block,bucket) run reservation
        // 32-bit payload: src(17) | x[src](7, bits 17..23) | local_dst(8, bits 24..31)
        for (int i = t; i < NBK; i += 256) bcnt[i] = 0;
        __syncthreads();
        int e0 = b * CHUNK;
        int n = min(e0 + CHUNK, N_EDGES) - e0;
        for (int i = t; i < n; i += 256) {
            int d = dst[e0 + i];
            int s = src[e0 + i];
            int xv = x[s];                      // random 4B read, 400KB L2-hot
            int k = d >> 8;
            earr[i] = (unsigned)s | ((unsigned)xv << 17) | ((unsigned)(d & 255) << 24);
            karr[i] = (unsigned short)k;
            atomicAdd(&bcnt[k], 1);
        }
        __syncthreads();
        for (int i = t; i < NBK; i += 256) {
            int c = bcnt[i];
            bbase[i] = i * CAP + (c ? atomicAdd(&cursor[i], c) : 0);
            bcnt[i] = 0;                        // reuse as local cursor
        }
        __syncthreads();
        for (int i = t; i < n; i += 256) {
            int k = karr[i];
            int off = atomicAdd(&bcnt[k], 1);
            edge8[bbase[k] + off] = earr[i];    // dense single-writer runs
        }
    } else if (b < SCAT_BLOCKS + GB) {
        // ---- graph boundaries (batch sorted)
        int i = (b - SCAT_BLOCKS) * 256 + t;
        if (i >= N_NODES) return;
        int bg = batch[i];
        int bp = (i == 0) ? -1 : batch[i - 1];
        for (int g = bp + 1; g <= bg; ++g) gstart[g] = i;
        if (i == N_NODES - 1)
            for (int g = bg + 1; g <= N_GRAPHS; ++g) gstart[g] = N_NODES;
    } else {
        // ---- precompute embW1l/embW1r + pack W2 B-fragments
        int vb = b - SCAT_BLOCKS - GB;
        // zero-row (legacy, harmless)
        if (vb == 0 && t < 16)
            ((unsigned*)(p8z + (size_t)N_NODES * 64))[t] = 0u;
        int wave = t >> 6, lane = t & 63;
        int v = vb * 4 + wave;
        if (v < VOCAB) {
            float er = emb[v * 64 + lane];       // lane = d
            float al = 0.f, ar = 0.f;
#pragma unroll 8
            for (int d = 0; d < 64; ++d) {
                float e = BCASTF(er, d);
                al += e * W1l[d * 64 + lane];
                ar += e * W1r[d * 64 + lane];
            }
            embW1l[v * 64 + lane] = al;
            embW1r[v * 64 + lane] = ar;
        }
        // W2 B-fragment packing: g = tt*1024 + h*512 + l*8 + j
        int g = vb * 256 + t;
        int j = g & 7, l = (g >> 3) & 63, h = (g >> 9) & 1, tt = g >> 10;
        int k = h * 32 + ((l >> 4) * 8) + j;
        int n = tt * 16 + (l & 15);
        float w = (n < 64) ? W2l[k * 64 + n] : W2r[k * 64 + (n - 64)];
        w2frag[g] = f2bf(w);
    }
}

// ---- per-bucket CSR build (rowstart/deg/col), dense writes ------
// col entry = src (17b) | x[src] (7b) -> sage1 needs no x gather at all
__global__ __launch_bounds__(256) void csr_kernel(
    const unsigned* __restrict__ edge8, const int* __restrict__ cursor,
    int* __restrict__ row_start, int* __restrict__ deg, int* __restrict__ col)
{
    __shared__ int cnt[CBUCKET];
    __shared__ int scn[CBUCKET];
    int b = blockIdx.x;                   // NBK blocks
    int t = threadIdx.x;
    int lo = b * CAP, hi = lo + cursor[b];  // cursor holds final fill count
    cnt[t] = 0;
    __syncthreads();
    for (int i = lo + t; i < hi; i += 256)
        atomicAdd(&cnt[edge8[i] >> 24], 1);
    __syncthreads();
    int v = cnt[t];
    scn[t] = v;
    __syncthreads();
    for (int off = 1; off < 256; off <<= 1) {
        int tmp = (t >= off) ? scn[t - off] : 0;
        __syncthreads();
        scn[t] += tmp;
        __syncthreads();
    }
    int excl = scn[t] - v;
    int node = b * CBUCKET + t;
    if (node < N_NODES) { row_start[node] = lo + excl; deg[node] = v; }
    cnt[t] = excl;                        // reuse as cursor
    __syncthreads();
    for (int i = lo + t; i < hi; i += 256) {
        unsigned e = edge8[i];
        int slot = atomicAdd(&cnt[e >> 24], 1);
        col[lo + slot] = (int)(e & 0xFFFFFF);   // src | x<<17 (24 bits)
    }
}

// ---- fused layer 1 + MFMA transform:
//   phase A: h1 = relu(mean_j(embW1l[x_j]) + b1 + embW1r[x_i])  ((c,g) layout,
//            ds_read_b128: one wave-instr covers 4 rows, 8 rows in flight)
//   phase B: [p|q] = h1 @ [W2l|W2r] via mfma_16x16x32_bf16; msbuf aliases elds
#define S1_NPW 8
__global__ __launch_bounds__(256) void sage1_kernel(
    const int* __restrict__ x, const float* __restrict__ embW1l,
    const float* __restrict__ embW1r, const float* __restrict__ b1,
    const int* __restrict__ row_start, const int* __restrict__ deg,
    const int* __restrict__ col, const unsigned short* __restrict__ w2frag,
    unsigned char* __restrict__ p8, unsigned short* __restrict__ q16)
{
    __shared__ float elds[VOCAB * 64];      // 32 KB; phase B aliases as msbuf
    int t = threadIdx.x;
    for (int i = t * 4; i < VOCAB * 64; i += 1024)
        *(float4*)&elds[i] = *(const float4*)&embW1l[i];
    __syncthreads();

    int wave = t >> 6, lane = t & 63;
    int block_base = blockIdx.x * (4 * S1_NPW);         // 3125*32 = 100000 exact
    int base_node = block_base + wave * S1_NPW;
    int c = lane & 15;          // feature quad: features 4c..4c+3
    int g = lane >> 4;          // row group 0..3
    float4 bias4 = ((const float4*)b1)[c];

    int rs[S1_NPW], dgs[S1_NPW], cidx[S1_NPW], xn[S1_NPW];
    float4 self4[S1_NPW];
#pragma unroll
    for (int n = 0; n < S1_NPW; ++n) {
        rs[n] = row_start[base_node + n];
        dgs[n] = deg[base_node + n];
        xn[n] = x[base_node + n];
    }
#pragma unroll
    for (int n = 0; n < S1_NPW; ++n) {
        cidx[n] = (lane < dgs[n]) ? col[rs[n] + lane] : 0;
        self4[n] = ((const float4*)(embW1r + xn[n] * 64))[c];
    }

    unsigned short* msbuf = (unsigned short*)elds;      // [32][72], aliases elds
    ushort4 h1row[S1_NPW];                              // lane's 4 features per node

    for (int n = 0; n < S1_NPW; ++n) {
        int dg = dgs[n];
        int dgc = (dg < 64) ? dg : 64;

        // 2 x ds_read_b128 per iter; each covers 4 rows across the groups
        float4 a0 = {0.f,0.f,0.f,0.f}, a1 = {0.f,0.f,0.f,0.f};
        for (int j = 0; j < dgc; j += 8) {
            int jj0 = j + g, jj1 = j + 4 + g;           // < 64 always
            int x0 = __shfl(cidx[n], jj0, 64) >> 17;
            int x1 = __shfl(cidx[n], jj1, 64) >> 17;
            float4 v0 = *(const float4*)&elds[x0 * 64 + c * 4];
            float4 v1 = *(const float4*)&elds[x1 * 64 + c * 4];
            if (jj0 < dgc) { a0.x += v0.x; a0.y += v0.y; a0.z += v0.z; a0.w += v0.w; }
            if (jj1 < dgc) { a1.x += v1.x; a1.y += v1.y; a1.z += v1.z; a1.w += v1.w; }
        }
        for (int k = 64; k < dg; ++k) {                 // deg>64 tail (rare)
            int cc = col[rs[n] + k] >> 17;
            float4 v = *(const float4*)&elds[cc * 64 + c * 4];
            if (g == 0) { a0.x += v.x; a0.y += v.y; a0.z += v.z; a0.w += v.w; }
        }
        float sx = a0.x + a1.x, sy = a0.y + a1.y, sz = a0.z + a1.z, sw = a0.w + a1.w;
        sx += __shfl_xor(sx, 16, 64); sx += __shfl_xor(sx, 32, 64);
        sy += __shfl_xor(sy, 16, 64); sy += __shfl_xor(sy, 32, 64);
        sz += __shfl_xor(sz, 16, 64); sz += __shfl_xor(sz, 32, 64);
        sw += __shfl_xor(sw, 16, 64); sw += __shfl_xor(sw, 32, 64);

        float inv = 1.0f / fmaxf((float)dg, 1.0f);
        h1row[n].x = f2bf(fmaxf(sx * inv + bias4.x + self4[n].x, 0.f));
        h1row[n].y = f2bf(fmaxf(sy * inv + bias4.y + self4[n].y, 0.f));
        h1row[n].z = f2bf(fmaxf(sz * inv + bias4.z + self4[n].z, 0.f));
        h1row[n].w = f2bf(fmaxf(sw * inv + bias4.w + self4[n].w, 0.f));
    }
    __syncthreads();                        // all elds reads complete

    // stage h1 rows into msbuf (stride 72 -> 16B-aligned rows); g==0 writes
    if (g == 0) {
#pragma unroll
        for (int n = 0; n < S1_NPW; ++n)
            *(ushort4*)&msbuf[(wave * S1_NPW + n) * 72 + c * 4] = h1row[n];
    }
    __syncthreads();

    // phase B: wave -> node-group (wave>>1), output tiles (wave&1)*4..+3
    int grp = wave >> 1, tbase = (wave & 1) * 4;
    int m = lane & 15, quad = lane >> 4;
    int base16g = block_base + grp * 16;
    const unsigned short* arow = &msbuf[(grp * 16 + m) * 72 + quad * 8];
    short8 a0 = *(const short8*)(arow);                 // k = quad*8 .. +7
    short8 a1 = *(const short8*)(arow + 32);            // k = 32+quad*8 .. +7

#pragma unroll
    for (int tt = tbase; tt < tbase + 4; ++tt) {
        short8 b0 = *(const short8*)(w2frag + tt * 1024 + lane * 8);
        short8 b1v = *(const short8*)(w2frag + tt * 1024 + 512 + lane * 8);
        f32x4 acc = {0.f, 0.f, 0.f, 0.f};
        acc = __builtin_amdgcn_mfma_f32_16x16x32_bf16(a0, b0, acc, 0, 0, 0);
        acc = __builtin_amdgcn_mfma_f32_16x16x32_bf16(a1, b1v, acc, 0, 0, 0);
        int o = tt * 16 + m;
        if (o < 64) {
            int pk01 = __builtin_amdgcn_cvt_pk_fp8_f32(acc[0], acc[1], 0, false);
            int pk23 = __builtin_amdgcn_cvt_pk_fp8_f32(acc[2], acc[3], 0, false);
            p8[(base16g + quad * 4 + 0) * 64 + o] = (unsigned char)(pk01 & 0xff);
            p8[(base16g + quad * 4 + 1) * 64 + o] = (unsigned char)((pk01 >> 8) & 0xff);
            p8[(base16g + quad * 4 + 2) * 64 + o] = (unsigned char)(pk23 & 0xff);
            p8[(base16g + quad * 4 + 3) * 64 + o] = (unsigned char)((pk23 >> 8) & 0xff);
        } else {
            int oc = o & 63;
#pragma unroll
            for (int i = 0; i < 4; ++i)
                q16[(base16g + quad * 4 + i) * 64 + oc] = f2bf(acc[i]);
        }
    }
}

// ---- sage2, edge-centric with LDS accumulators --------------------------
//   One block per HALF-bucket (128 nodes): acc[128][64] f32 = 32 KB LDS.
//   Thread owns whole edges (strided over the bucket's edge8 run): its
//   4x16B p-row loads are fully independent -> no cross-lane addr chains,
//   ~40 loads in flight/thread. Scatter-add via ds_add_f32 (atomicAdd,
//   no return, no dependency chain). Row-stride-64 would be a 32-way bank
//   conflict at any static step (G4), so 4-float groups are XOR-swizzled
//   by (row&15); epilogue reads with the same XOR (both-sides rule).
//   h2 = relu(acc/deg + b2 + q_i); gsum[batch] += h2 @ Wout (once/node).
#define S2B_NODES 128
__global__ __launch_bounds__(256) void sage2_kernel(
    const unsigned char* __restrict__ p, const unsigned short* __restrict__ q,
    const unsigned* __restrict__ edge8, const int* __restrict__ cursor,
    const int* __restrict__ deg, const float* __restrict__ b2,
    const float* __restrict__ Wout, const int* __restrict__ batch,
    float* __restrict__ gsum)
{
    __shared__ float acc[S2B_NODES * 64];       // 32 KB
    int blk = blockIdx.x;
    int bucket = blk >> 1;
    int half = blk & 1;                         // local_dst bit 7
    int t = threadIdx.x;

    for (int i = t * 4; i < S2B_NODES * 64; i += 1024)
        *(float4*)&acc[i] = (float4){0.f, 0.f, 0.f, 0.f};
    __syncthreads();

    int lo = bucket * CAP;
    int ecnt = cursor[bucket];

    for (int i = t; i < ecnt; i += 256) {
        unsigned e = edge8[lo + i];
        int ld = (int)(e >> 24);
        if ((ld >> 7) != half) continue;        // other half-block handles it
        int srcn = (int)(e & 0x1FFFF);
        int r = ld & (S2B_NODES - 1);
        const uint4* row = (const uint4*)(p + ((size_t)srcn << 6));
        uint4 w0 = row[0], w1 = row[1], w2 = row[2], w3 = row[3];
        float* ap = &acc[r * 64];
        int s4 = (r & 15) << 2;                 // 4-float-group XOR swizzle
#define ADD4(word, kb) { \
        f32x2 lo_ = __builtin_amdgcn_cvt_pk_f32_fp8((int)(word), false); \
        f32x2 hi_ = __builtin_amdgcn_cvt_pk_f32_fp8((int)(word), true);  \
        float* gp_ = ap + ((kb) ^ s4); \
        atomicAdd(gp_ + 0, lo_.x); atomicAdd(gp_ + 1, lo_.y); \
        atomicAdd(gp_ + 2, hi_.x); atomicAdd(gp_ + 3, hi_.y); }
        ADD4(w0.x,  0) ADD4(w0.y,  4) ADD4(w0.z,  8) ADD4(w0.w, 12)
        ADD4(w1.x, 16) ADD4(w1.y, 20) ADD4(w1.z, 24) ADD4(w1.w, 28)
        ADD4(w2.x, 32) ADD4(w2.y, 36) ADD4(w2.z, 40) ADD4(w2.w, 44)
        ADD4(w3.x, 48) ADD4(w3.y, 52) ADD4(w3.z, 56) ADD4(w3.w, 60)
#undef ADD4
    }
    __syncthreads();

    // ---- epilogue: thread t (<128) owns node; sequential feature groups,
    //      XOR-swizzled LDS address spreads banks across the 16-lane groups
    if (t < S2B_NODES) {
        int node = bucket * CBUCKET + half * S2B_NODES + t;
        if (node < N_NODES) {
            int dg = deg[node];
            int grp = batch[node];
            float inv = 1.0f / fmaxf((float)dg, 1.0f);
            const float* ap = &acc[t * 64];
            int s4 = (t & 15) << 2;
            float s0 = 0.f, s1 = 0.f;
#pragma unroll
            for (int j = 0; j < 16; ++j) {      // j = true feature group
                float4 v = *(const float4*)(ap + ((j << 2) ^ s4));
                float4 bb = ((const float4*)b2)[j];
                ushort4 qv = *(const ushort4*)(q + ((size_t)node << 6) + (j << 2));
                float4 wA = ((const float4*)Wout)[j * 2];
                float4 wB = ((const float4*)Wout)[j * 2 + 1];
                float h0 = fmaxf(v.x * inv + bb.x + bf2f(qv.x), 0.f);
                float h1 = fmaxf(v.y * inv + bb.y + bf2f(qv.y), 0.f);
                float h2 = fmaxf(v.z * inv + bb.z + bf2f(qv.z), 0.f);
                float h3 = fmaxf(v.w * inv + bb.w + bf2f(qv.w), 0.f);
                s0 += h0 * wA.x + h1 * wA.z + h2 * wB.x + h3 * wB.z;
                s1 += h0 * wA.y + h1 * wA.w + h2 * wB.y + h3 * wB.w;
            }
            atomicAdd(&gsum[(grp << 1) + 0], s0);
            atomicAdd(&gsum[(grp << 1) + 1], s1);
        }
    }
}

// ---------------- finalize: out = gsum/cnt + bout ----------------
__global__ __launch_bounds__(256) void finalize_kernel(
    const float* __restrict__ gsum, const int* __restrict__ gstart,
    const float* __restrict__ bout, float* __restrict__ out)
{
    int g = blockIdx.x * 256 + threadIdx.x;
    if (g >= N_GRAPHS) return;
    int cnt = gstart[g + 1] - gstart[g];
    float inv = 1.0f / fmaxf((float)cnt, 1.0f);
    out[g * 2 + 0] = gsum[g * 2 + 0] * inv + bout[0];
    out[g * 2 + 1] = gsum[g * 2 + 1] * inv + bout[1];
}

extern "C" void kernel_launch(void* const* d_in, const int* in_sizes, int n_in,
                              void* d_out, int out_size, void* d_ws, size_t ws_size,
                              hipStream_t stream) {
    const int*   x    = (const int*)  d_in[0];
    const int*   ei   = (const int*)  d_in[1];
    const int*   batch= (const int*)  d_in[2];
    const float* emb  = (const float*)d_in[3];
    const float* W1l  = (const float*)d_in[4];
    const float* b1   = (const float*)d_in[5];
    const float* W1r  = (const float*)d_in[6];
    const float* W2l  = (const float*)d_in[7];
    const float* b2   = (const float*)d_in[8];
    const float* W2r  = (const float*)d_in[9];
    const float* Wout = (const float*)d_in[10];
    const float* bout = (const float*)d_in[11];
    float* out = (float*)d_out;

    const int* src = ei;
    const int* dst = ei + N_EDGES;

    char* ws = (char*)d_ws;
    size_t off = 0;
    unsigned char*  p8     = (unsigned char*) (ws + off); off += (size_t)N_NODES * 64 + 64; // +64B zero row
    unsigned short* q16    = (unsigned short*)(ws + off); off += (size_t)N_NODES * 64 * 2;  // 12.8 MB
    unsigned short* w2frag = (unsigned short*)(ws + off); off += (size_t)8192 * 2;
    float*    embW1l = (float*)   (ws + off); off += (size_t)VOCAB * 64 * 4;
    float*    embW1r = (float*)   (ws + off); off += (size_t)VOCAB * 64 * 4;
    int*      rowst  = (int*)     (ws + off); off += (size_t)N_NODES * 4;
    int*      deg    = (int*)     (ws + off); off += (size_t)N_NODES * 4;
    int*      col    = (int*)     (ws + off); off += (size_t)(NBK * CAP + 256) * 4;   // 6.4 MB
    unsigned* edge8  = (unsigned*)(ws + off); off += (size_t)NBK * CAP * 4;           // 6.4 MB
    int*      gstart = (int*)     (ws + off); off += (size_t)(N_GRAPHS + 1) * 4;
    // contiguous zero region: cursor | gsum (one memset)
    int*      cursor = (int*)     (ws + off); off += (size_t)NBK * 4;
    float*    gsum   = (float*)   (ws + off); off += (size_t)N_GRAPHS * 2 * 4;

    hipMemsetAsync(cursor, 0, (size_t)NBK * 4 + (size_t)N_GRAPHS * 2 * 4, stream);

    scatter_kernel<<<SCAT_BLOCKS + GB + 32, 256, 0, stream>>>(
        src, dst, x, cursor, edge8,
        batch, gstart, emb, W1l, W1r, W2l, W2r, embW1l, embW1r, w2frag, p8);
    csr_kernel<<<NBK, 256, 0, stream>>>(edge8, cursor, rowst, deg, col);
    sage1_kernel<<<N_NODES / (4 * S1_NPW), 256, 0, stream>>>(
        x, embW1l, embW1r, b1, rowst, deg, col, w2frag, p8, q16);
    sage2_kernel<<<NBK * 2, 256, 0, stream>>>(
        p8, q16, edge8, cursor, deg, b2, Wout, batch, gsum);
    finalize_kernel<<<(N_GRAPHS + 255) / 256, 256, 0, stream>>>(gsum, gstart, bout, out);
}

// Round 4
// 190.939 us; speedup vs baseline: 3.0873x; 3.0873x over previous
//
#include <hip/hip_runtime.h>
#include <hip/hip_bf16.h>

#define N_NODES 100000
#define N_EDGES 1000000
#define EMB 64
#define HID 64
#define VOCAB 128
#define N_GRAPHS 2048

#define CBUCKET 256                                    // nodes per bucket
#define NBK ((N_NODES + CBUCKET - 1) / CBUCKET)        // 391
#define CAP 4096                                       // slots per bucket (E[cnt]=2560, 30 sigma)
#define CHUNK 4096
#define SCAT_BLOCKS ((N_EDGES + CHUNK - 1) / CHUNK)    // 245
#define GB ((N_NODES + 255) / 256)                     // 391 gstart blocks

#define BCASTF(v, l) __int_as_float(__builtin_amdgcn_readlane(__float_as_int(v), (l)))

typedef __attribute__((ext_vector_type(8))) short short8;
typedef __attribute__((ext_vector_type(4))) float f32x4;
typedef __attribute__((ext_vector_type(2))) float f32x2;

__device__ __forceinline__ float bf2f(unsigned short u) {
    return __uint_as_float((unsigned)u << 16);
}
__device__ __forceinline__ unsigned short f2bf(float f) {
    return __bfloat16_as_ushort(__float2bfloat16(f));
}

// ---- merged scatter + setup: blocks [0,245) scatter, [245,636) gstart,
//      [636,668) precompute. cursor/gsum pre-zeroed by one memset.
__global__ __launch_bounds__(256) void scatter_kernel(
    const int* __restrict__ src, const int* __restrict__ dst,
    const int* __restrict__ x,
    int* __restrict__ cursor, unsigned* __restrict__ edge8,
    const int* __restrict__ batch, int* __restrict__ gstart,
    const float* __restrict__ emb, const float* __restrict__ W1l,
    const float* __restrict__ W1r,
    const float* __restrict__ W2l, const float* __restrict__ W2r,
    float* __restrict__ embW1l, float* __restrict__ embW1r,
    unsigned short* __restrict__ w2frag, unsigned char* __restrict__ p8z)
{
    __shared__ unsigned earr[CHUNK];            // 16 KB packed payload
    __shared__ unsigned short karr[CHUNK];      // 8 KB bucket key (0..390)
    __shared__ int bcnt[NBK];
    __shared__ int bbase[NBK];
    int b = blockIdx.x;
    int t = threadIdx.x;

    if (b < SCAT_BLOCKS) {
        // ---- scatter: LDS-staged chunk, per-(block,bucket) run reservation
        // 32-bit payload: src(17) | x[src](7, bits 17..23) | local_dst(8, bits 24..31)
        for (int i = t; i < NBK; i += 256) bcnt[i] = 0;
        __syncthreads();
        int e0 = b * CHUNK;
        int n = min(e0 + CHUNK, N_EDGES) - e0;
        for (int i = t; i < n; i += 256) {
            int d = dst[e0 + i];
            int s = src[e0 + i];
            int xv = x[s];                      // random 4B read, 400KB L2-hot
            int k = d >> 8;
            earr[i] = (unsigned)s | ((unsigned)xv << 17) | ((unsigned)(d & 255) << 24);
            karr[i] = (unsigned short)k;
            atomicAdd(&bcnt[k], 1);
        }
        __syncthreads();
        for (int i = t; i < NBK; i += 256) {
            int c = bcnt[i];
            bbase[i] = i * CAP + (c ? atomicAdd(&cursor[i], c) : 0);
            bcnt[i] = 0;                        // reuse as local cursor
        }
        __syncthreads();
        for (int i = t; i < n; i += 256) {
            int k = karr[i];
            int off = atomicAdd(&bcnt[k], 1);
            edge8[bbase[k] + off] = earr[i];    // dense single-writer runs
        }
    } else if (b < SCAT_BLOCKS + GB) {
        // ---- graph boundaries (batch sorted)
        int i = (b - SCAT_BLOCKS) * 256 + t;
        if (i >= N_NODES) return;
        int bg = batch[i];
        int bp = (i == 0) ? -1 : batch[i - 1];
        for (int g = bp + 1; g <= bg; ++g) gstart[g] = i;
        if (i == N_NODES - 1)
            for (int g = bg + 1; g <= N_GRAPHS; ++g) gstart[g] = N_NODES;
    } else {
        // ---- precompute embW1l/embW1r + pack W2 B-fragments
        int vb = b - SCAT_BLOCKS - GB;
        // zero-row for sage2's branch-free gather (fp8 0x00 == +0.0)
        if (vb == 0 && t < 16)
            ((unsigned*)(p8z + (size_t)N_NODES * 64))[t] = 0u;
        int wave = t >> 6, lane = t & 63;
        int v = vb * 4 + wave;
        if (v < VOCAB) {
            float er = emb[v * 64 + lane];       // lane = d
            float al = 0.f, ar = 0.f;
#pragma unroll 8
            for (int d = 0; d < 64; ++d) {
                float e = BCASTF(er, d);
                al += e * W1l[d * 64 + lane];
                ar += e * W1r[d * 64 + lane];
            }
            embW1l[v * 64 + lane] = al;
            embW1r[v * 64 + lane] = ar;
        }
        // W2 B-fragment packing: g = tt*1024 + h*512 + l*8 + j
        int g = vb * 256 + t;
        int j = g & 7, l = (g >> 3) & 63, h = (g >> 9) & 1, tt = g >> 10;
        int k = h * 32 + ((l >> 4) * 8) + j;
        int n = tt * 16 + (l & 15);
        float w = (n < 64) ? W2l[k * 64 + n] : W2r[k * 64 + (n - 64)];
        w2frag[g] = f2bf(w);
    }
}

// ---- per-bucket CSR build (rowstart/deg/col), dense writes ------
// col entry = src (17b) | x[src] (7b) -> sage2 gathers need no extra x read.
// Blocks 0..7 additionally pack W1 B-fragments (K=256: [embW1l;embW1r]) --
// must be a dispatch AFTER scatter (embW1l is produced there).
__global__ __launch_bounds__(256) void csr_kernel(
    const unsigned* __restrict__ edge8, const int* __restrict__ cursor,
    int* __restrict__ row_start, int* __restrict__ deg, int* __restrict__ col,
    const float* __restrict__ embW1l, const float* __restrict__ embW1r,
    unsigned short* __restrict__ w1frag)
{
    __shared__ int cnt[CBUCKET];
    __shared__ int scn[CBUCKET];
    int b = blockIdx.x;                   // NBK blocks
    int t = threadIdx.x;

    if (b < 8) {
        // w1frag[( (kf*4+nt)*64 + l)*8 + j] = bf16 of B[k][n],
        //   k = kf*32 + (l>>4)*8 + j, n = nt*16 + (l&15); k>=128 -> embW1r
        int g0 = (b * 256 + t) * 8;
#pragma unroll
        for (int j = 0; j < 8; ++j) {
            int g = g0 + j;
            int fi = g >> 9;
            int kf = fi >> 2, nt = fi & 3;
            int l = (g >> 3) & 63, jj = g & 7;
            int kg = kf * 32 + ((l >> 4) << 3) + jj;
            int n = nt * 16 + (l & 15);
            float w = (kg < 128) ? embW1l[kg * 64 + n] : embW1r[(kg - 128) * 64 + n];
            w1frag[g] = f2bf(w);
        }
    }

    int lo = b * CAP, hi = lo + cursor[b];  // cursor holds final fill count
    cnt[t] = 0;
    __syncthreads();
    for (int i = lo + t; i < hi; i += 256)
        atomicAdd(&cnt[edge8[i] >> 24], 1);
    __syncthreads();
    int v = cnt[t];
    scn[t] = v;
    __syncthreads();
    for (int off = 1; off < 256; off <<= 1) {
        int tmp = (t >= off) ? scn[t - off] : 0;
        __syncthreads();
        scn[t] += tmp;
        __syncthreads();
    }
    int excl = scn[t] - v;
    int node = b * CBUCKET + t;
    if (node < N_NODES) { row_start[node] = lo + excl; deg[node] = v; }
    cnt[t] = excl;                        // reuse as cursor
    __syncthreads();
    for (int i = lo + t; i < hi; i += 256) {
        unsigned e = edge8[i];
        int slot = atomicAdd(&cnt[e >> 24], 1);
        col[lo + slot] = (int)(e & 0xFFFFFF);   // src | x<<17 (24 bits)
    }
}

// ---- sage1, histogram-MFMA form ----------------------------------------
// mean_j embW1l[x_j] = (hist(node,:) @ embW1l) / deg  (x_j in [0,128))
// self term           = onehot(x_i) @ embW1r
// One block per HALF-bucket (128 nodes):
//   1. hist[128 nodes][128 vocab] u8 in LDS, built edge-centric: ONE packed
//      ds_add_u32 per edge (counts <= deg <= ~40, byte-safe). Word index is
//      XOR-swizzled by (row&7)<<2 so A-frag ds_read_b64 at a fixed column
//      is not a 16-way bank conflict (read applies the same XOR).
//   2. phase A MFMA (K=256): acc_agg (counts, exact bf16) over k=0..127,
//      acc_self (one-hot) over k=128..255; h1 = relu(acc_agg*invdeg +
//      acc_self + b1); f32 accum so only B is bf16-rounded.
//   3. phase B: [p|q] = h1 @ [W2l|W2r] via w2frag (unchanged pattern).
__global__ __launch_bounds__(256) void sage1_kernel(
    const int* __restrict__ x, const int* __restrict__ deg,
    const unsigned* __restrict__ edge8, const int* __restrict__ cursor,
    const unsigned short* __restrict__ w1frag,
    const unsigned short* __restrict__ w2frag, const float* __restrict__ b1,
    unsigned char* __restrict__ p8, unsigned short* __restrict__ q16)
{
    __shared__ unsigned hist[128 * 32];         // 16 KB u8[128][128], swizzled words
    __shared__ unsigned short msbuf[128 * 72];  // 18 KB h1 bf16, stride 72
    __shared__ int xl[128];
    __shared__ float invd[128];

    int blk = blockIdx.x, bucket = blk >> 1, half = blk & 1;
    int t = threadIdx.x;
    int nbase = bucket * CBUCKET + half * 128;

    for (int i = t * 4; i < 128 * 32; i += 1024)
        *(uint4*)&hist[i] = (uint4){0u, 0u, 0u, 0u};
    if (t < 128) {
        int node = nbase + t;
        int dv = (node < N_NODES) ? deg[node] : 0;
        invd[t] = 1.0f / fmaxf((float)dv, 1.0f);
        xl[t] = (node < N_NODES) ? x[node] : 0;
    }
    __syncthreads();

    int lo = bucket * CAP, ecnt = cursor[bucket];
    for (int i = t; i < ecnt; i += 256) {
        unsigned e = edge8[lo + i];
        int ld = (int)(e >> 24);
        if ((ld >> 7) == half) {
            int r = ld & 127;
            int xv = (int)((e >> 17) & 127);
            int wc = (xv >> 2) ^ ((r & 7) << 2);        // word swizzle
            atomicAdd(&hist[r * 32 + wc], 1u << ((xv & 3) * 8));
        }
    }
    __syncthreads();

    int wave = t >> 6, lane = t & 63;
    int m = lane & 15;                  // A row / C col index
    int qd = lane >> 4;                 // k-subchunk / C row-group
    int hswz = (m & 7) << 2;            // row m's word swizzle

#pragma unroll
    for (int rt = wave * 2; rt < wave * 2 + 2; ++rt) {
        // ---- build A-fragments: counts (kf 0..3) + one-hot (kf 4..7) ----
        short8 acnt[4], aself[4];
#pragma unroll
        for (int kf = 0; kf < 4; ++kf) {
            int w0 = (kf * 8 + qd * 2) ^ hswz;          // even ^ (bits>=2) stays even
            uint2 u = *(const uint2*)&hist[(rt * 16 + m) * 32 + w0];
            short8 f;
            f[0] = (short)f2bf((float)(u.x & 255));
            f[1] = (short)f2bf((float)((u.x >> 8) & 255));
            f[2] = (short)f2bf((float)((u.x >> 16) & 255));
            f[3] = (short)f2bf((float)(u.x >> 24));
            f[4] = (short)f2bf((float)(u.y & 255));
            f[5] = (short)f2bf((float)((u.y >> 8) & 255));
            f[6] = (short)f2bf((float)((u.y >> 16) & 255));
            f[7] = (short)f2bf((float)(u.y >> 24));
            acnt[kf] = f;
        }
        int xv = xl[rt * 16 + m];
#pragma unroll
        for (int kf = 0; kf < 4; ++kf) {
            int v = xv - kf * 32 - qd * 8;              // in [0,8) -> hit at j=v
            short8 f;
#pragma unroll
            for (int j = 0; j < 8; ++j)
                f[j] = (v == j) ? (short)0x3F80 : (short)0;
            aself[kf] = f;
        }
        float iv0 = invd[rt * 16 + qd * 4 + 0];
        float iv1 = invd[rt * 16 + qd * 4 + 1];
        float iv2 = invd[rt * 16 + qd * 4 + 2];
        float iv3 = invd[rt * 16 + qd * 4 + 3];

#pragma unroll
        for (int nt = 0; nt < 4; ++nt) {
            f32x4 accA = {0.f, 0.f, 0.f, 0.f};
            f32x4 accS = {0.f, 0.f, 0.f, 0.f};
#pragma unroll
            for (int kf = 0; kf < 4; ++kf) {
                short8 bA = *(const short8*)(w1frag + ((kf * 4 + nt) * 64 + lane) * 8);
                accA = __builtin_amdgcn_mfma_f32_16x16x32_bf16(acnt[kf], bA, accA, 0, 0, 0);
            }
#pragma unroll
            for (int kf = 0; kf < 4; ++kf) {
                short8 bS = *(const short8*)(w1frag + (((kf + 4) * 4 + nt) * 64 + lane) * 8);
                accS = __builtin_amdgcn_mfma_f32_16x16x32_bf16(aself[kf], bS, accS, 0, 0, 0);
            }
            int c = nt * 16 + m;
            float b1c = b1[c];
            int rb = rt * 16 + qd * 4;
            msbuf[(rb + 0) * 72 + c] = f2bf(fmaxf(accA[0] * iv0 + accS[0] + b1c, 0.f));
            msbuf[(rb + 1) * 72 + c] = f2bf(fmaxf(accA[1] * iv1 + accS[1] + b1c, 0.f));
            msbuf[(rb + 2) * 72 + c] = f2bf(fmaxf(accA[2] * iv2 + accS[2] + b1c, 0.f));
            msbuf[(rb + 3) * 72 + c] = f2bf(fmaxf(accA[3] * iv3 + accS[3] + b1c, 0.f));
        }
    }
    __syncthreads();

    // ---- phase B: [p|q] = h1 @ [W2l|W2r] (w2frag pattern, proven) ----
#pragma unroll
    for (int rt = wave * 2; rt < wave * 2 + 2; ++rt) {
        const unsigned short* arow = &msbuf[(rt * 16 + m) * 72 + qd * 8];
        short8 a0 = *(const short8*)(arow);             // k = qd*8 .. +7
        short8 a1 = *(const short8*)(arow + 32);        // k = 32+qd*8 .. +7
        int rowb = nbase + rt * 16 + qd * 4;

#pragma unroll
        for (int tt = 0; tt < 8; ++tt) {
            short8 b0 = *(const short8*)(w2frag + tt * 1024 + lane * 8);
            short8 b1v = *(const short8*)(w2frag + tt * 1024 + 512 + lane * 8);
            f32x4 acc = {0.f, 0.f, 0.f, 0.f};
            acc = __builtin_amdgcn_mfma_f32_16x16x32_bf16(a0, b0, acc, 0, 0, 0);
            acc = __builtin_amdgcn_mfma_f32_16x16x32_bf16(a1, b1v, acc, 0, 0, 0);
            int o = tt * 16 + m;
            if (o < 64) {
                int pk01 = __builtin_amdgcn_cvt_pk_fp8_f32(acc[0], acc[1], 0, false);
                int pk23 = __builtin_amdgcn_cvt_pk_fp8_f32(acc[2], acc[3], 0, false);
                if (rowb + 0 < N_NODES) p8[(rowb + 0) * 64 + o] = (unsigned char)(pk01 & 0xff);
                if (rowb + 1 < N_NODES) p8[(rowb + 1) * 64 + o] = (unsigned char)((pk01 >> 8) & 0xff);
                if (rowb + 2 < N_NODES) p8[(rowb + 2) * 64 + o] = (unsigned char)(pk23 & 0xff);
                if (rowb + 3 < N_NODES) p8[(rowb + 3) * 64 + o] = (unsigned char)((pk23 >> 8) & 0xff);
            } else {
                int oc = o & 63;
#pragma unroll
                for (int i = 0; i < 4; ++i)
                    if (rowb + i < N_NODES)
                        q16[(rowb + i) * 64 + oc] = f2bf(acc[i]);
            }
        }
    }
}

// ---- sage2: round-2 proven layout (16 lanes/row, shfl addr broadcast),
//   node pairs with fixed 16-row window; cidx pre-masked to zero row.
#define S2_NPW 8
#define ZROW N_NODES
__global__ __launch_bounds__(256, 6) void sage2_kernel(
    const unsigned char* __restrict__ p, const unsigned short* __restrict__ q,
    const int* __restrict__ row_start, const int* __restrict__ deg,
    const int* __restrict__ col, const float* __restrict__ b2,
    const float* __restrict__ Wout, const int* __restrict__ batch,
    float* __restrict__ gsum)
{
    int t = threadIdx.x;
    int wave = t >> 6, lane = t & 63;
    int base_node = (blockIdx.x * 4 + wave) * S2_NPW;   // exact cover
    int c = lane & 15;          // feature quad: features 4c..4c+3
    int g = lane >> 4;          // row group 0..3

    float4 b2v = ((const float4*)b2)[c];
    float4 w01 = ((const float4*)Wout)[c * 2];
    float4 w23 = ((const float4*)Wout)[c * 2 + 1];

    int rs[S2_NPW], dgs[S2_NPW], cidx[S2_NPW];
#pragma unroll
    for (int n = 0; n < S2_NPW; ++n) {
        rs[n] = row_start[base_node + n];
        dgs[n] = deg[base_node + n];
    }
#pragma unroll
    for (int n = 0; n < S2_NPW; ++n)
        cidx[n] = (lane < dgs[n]) ? (col[rs[n] + lane] & 0x1FFFF) : ZROW;

#define ACC(a, v) { f32x2 f01_ = __builtin_amdgcn_cvt_pk_f32_fp8((int)(v), false); \
                    f32x2 f23_ = __builtin_amdgcn_cvt_pk_f32_fp8((int)(v), true);  \
                    (a).x += f01_.x; (a).y += f01_.y; (a).z += f23_.x; (a).w += f23_.y; }

#pragma unroll
    for (int n = 0; n < S2_NPW; n += 2) {
        int dgA = dgs[n], dgB = dgs[n + 1];

        int iA0 = __shfl(cidx[n], g, 64);
        int iA1 = __shfl(cidx[n], 4 + g, 64);
        int iA2 = __shfl(cidx[n], 8 + g, 64);
        int iA3 = __shfl(cidx[n], 12 + g, 64);
        int iB0 = __shfl(cidx[n + 1], g, 64);
        int iB1 = __shfl(cidx[n + 1], 4 + g, 64);
        int iB2 = __shfl(cidx[n + 1], 8 + g, 64);
        int iB3 = __shfl(cidx[n + 1], 12 + g, 64);

        unsigned vA0 = *(const unsigned*)(p + (size_t)iA0 * 64 + c * 4);
        unsigned vA1 = *(const unsigned*)(p + (size_t)iA1 * 64 + c * 4);
        unsigned vA2 = *(const unsigned*)(p + (size_t)iA2 * 64 + c * 4);
        unsigned vA3 = *(const unsigned*)(p + (size_t)iA3 * 64 + c * 4);
        unsigned vB0 = *(const unsigned*)(p + (size_t)iB0 * 64 + c * 4);
        unsigned vB1 = *(const unsigned*)(p + (size_t)iB1 * 64 + c * 4);
        unsigned vB2 = *(const unsigned*)(p + (size_t)iB2 * 64 + c * 4);
        unsigned vB3 = *(const unsigned*)(p + (size_t)iB3 * 64 + c * 4);

        float4 aA = {0.f,0.f,0.f,0.f}, aB = {0.f,0.f,0.f,0.f};
        ACC(aA, vA0) ACC(aA, vA1) ACC(aA, vA2) ACC(aA, vA3)
        ACC(aB, vB0) ACC(aB, vB1) ACC(aB, vB2) ACC(aB, vB3)

        for (int j = 16; j < dgA; j += 8) {
            int i0 = __shfl(cidx[n], j + g, 64);
            int i1 = __shfl(cidx[n], j + 4 + g, 64);
            unsigned v0 = *(const unsigned*)(p + (size_t)i0 * 64 + c * 4);
            unsigned v1 = *(const unsigned*)(p + (size_t)i1 * 64 + c * 4);
            ACC(aA, v0) ACC(aA, v1)
        }
        for (int j = 16; j < dgB; j += 8) {
            int i0 = __shfl(cidx[n + 1], j + g, 64);
            int i1 = __shfl(cidx[n + 1], j + 4 + g, 64);
            unsigned v0 = *(const unsigned*)(p + (size_t)i0 * 64 + c * 4);
            unsigned v1 = *(const unsigned*)(p + (size_t)i1 * 64 + c * 4);
            ACC(aB, v0) ACC(aB, v1)
        }
        for (int k = 64; k < dgA; ++k) {
            int r = col[rs[n] + k] & 0x1FFFF;
            unsigned v = *(const unsigned*)(p + (size_t)r * 64 + c * 4);
            if (g == 0) ACC(aA, v)
        }
        for (int k = 64; k < dgB; ++k) {
            int r = col[rs[n + 1] + k] & 0x1FFFF;
            unsigned v = *(const unsigned*)(p + (size_t)r * 64 + c * 4);
            if (g == 0) ACC(aB, v)
        }

        aA.x += __shfl_xor(aA.x, 16, 64); aA.y += __shfl_xor(aA.y, 16, 64);
        aA.z += __shfl_xor(aA.z, 16, 64); aA.w += __shfl_xor(aA.w, 16, 64);
        aB.x += __shfl_xor(aB.x, 16, 64); aB.y += __shfl_xor(aB.y, 16, 64);
        aB.z += __shfl_xor(aB.z, 16, 64); aB.w += __shfl_xor(aB.w, 16, 64);
        aA.x += __shfl_xor(aA.x, 32, 64); aA.y += __shfl_xor(aA.y, 32, 64);
        aA.z += __shfl_xor(aA.z, 32, 64); aA.w += __shfl_xor(aA.w, 32, 64);
        aB.x += __shfl_xor(aB.x, 32, 64); aB.y += __shfl_xor(aB.y, 32, 64);
        aB.z += __shfl_xor(aB.z, 32, 64); aB.w += __shfl_xor(aB.w, 32, 64);

#pragma unroll
        for (int e = 0; e < 2; ++e) {
            int node = base_node + n + e;
            int dg = (e == 0) ? dgA : dgB;
            float4 a = (e == 0) ? aA : aB;
            float inv = 1.0f / fmaxf((float)dg, 1.0f);
            ushort4 qv = *(const ushort4*)(q + node * 64 + c * 4);
            float h0 = fmaxf(a.x * inv + b2v.x + bf2f(qv.x), 0.f);
            float h1 = fmaxf(a.y * inv + b2v.y + bf2f(qv.y), 0.f);
            float h2 = fmaxf(a.z * inv + b2v.z + bf2f(qv.z), 0.f);
            float h3 = fmaxf(a.w * inv + b2v.w + bf2f(qv.w), 0.f);

            float p0 = h0 * w01.x + h1 * w01.z + h2 * w23.x + h3 * w23.z;
            float p1 = h0 * w01.y + h1 * w01.w + h2 * w23.y + h3 * w23.w;
            if (g != 0) { p0 = 0.f; p1 = 0.f; }         // groups duplicate
            p0 += __shfl_down(p0, 8, 64);  p1 += __shfl_down(p1, 8, 64);
            p0 += __shfl_down(p0, 4, 64);  p1 += __shfl_down(p1, 4, 64);
            p0 += __shfl_down(p0, 2, 64);  p1 += __shfl_down(p1, 2, 64);
            p0 += __shfl_down(p0, 1, 64);  p1 += __shfl_down(p1, 1, 64);
            if (lane == 0) {
                int grp = batch[node];
                atomicAdd(&gsum[grp * 2 + 0], p0);
                atomicAdd(&gsum[grp * 2 + 1], p1);
            }
        }
    }
#undef ACC
}

// ---------------- finalize: out = gsum/cnt + bout ----------------
__global__ __launch_bounds__(256) void finalize_kernel(
    const float* __restrict__ gsum, const int* __restrict__ gstart,
    const float* __restrict__ bout, float* __restrict__ out)
{
    int g = blockIdx.x * 256 + threadIdx.x;
    if (g >= N_GRAPHS) return;
    int cnt = gstart[g + 1] - gstart[g];
    float inv = 1.0f / fmaxf((float)cnt, 1.0f);
    out[g * 2 + 0] = gsum[g * 2 + 0] * inv + bout[0];
    out[g * 2 + 1] = gsum[g * 2 + 1] * inv + bout[1];
}

extern "C" void kernel_launch(void* const* d_in, const int* in_sizes, int n_in,
                              void* d_out, int out_size, void* d_ws, size_t ws_size,
                              hipStream_t stream) {
    const int*   x    = (const int*)  d_in[0];
    const int*   ei   = (const int*)  d_in[1];
    const int*   batch= (const int*)  d_in[2];
    const float* emb  = (const float*)d_in[3];
    const float* W1l  = (const float*)d_in[4];
    const float* b1   = (const float*)d_in[5];
    const float* W1r  = (const float*)d_in[6];
    const float* W2l  = (const float*)d_in[7];
    const float* b2   = (const float*)d_in[8];
    const float* W2r  = (const float*)d_in[9];
    const float* Wout = (const float*)d_in[10];
    const float* bout = (const float*)d_in[11];
    float* out = (float*)d_out;

    const int* src = ei;
    const int* dst = ei + N_EDGES;

    char* ws = (char*)d_ws;
    size_t off = 0;
    unsigned char*  p8     = (unsigned char*) (ws + off); off += (size_t)N_NODES * 64 + 64; // +64B zero row
    unsigned short* q16    = (unsigned short*)(ws + off); off += (size_t)N_NODES * 64 * 2;  // 12.8 MB
    unsigned short* w2frag = (unsigned short*)(ws + off); off += (size_t)8192 * 2;
    unsigned short* w1frag = (unsigned short*)(ws + off); off += (size_t)16384 * 2;         // 32 KB
    float*    embW1l = (float*)   (ws + off); off += (size_t)VOCAB * 64 * 4;
    float*    embW1r = (float*)   (ws + off); off += (size_t)VOCAB * 64 * 4;
    int*      rowst  = (int*)     (ws + off); off += (size_t)N_NODES * 4;
    int*      deg    = (int*)     (ws + off); off += (size_t)N_NODES * 4;
    int*      col    = (int*)     (ws + off); off += (size_t)(NBK * CAP + 256) * 4;   // 6.4 MB
    unsigned* edge8  = (unsigned*)(ws + off); off += (size_t)NBK * CAP * 4;           // 6.4 MB
    int*      gstart = (int*)     (ws + off); off += (size_t)(N_GRAPHS + 1) * 4;
    // contiguous zero region: cursor | gsum (one memset)
    int*      cursor = (int*)     (ws + off); off += (size_t)NBK * 4;
    float*    gsum   = (float*)   (ws + off); off += (size_t)N_GRAPHS * 2 * 4;

    hipMemsetAsync(cursor, 0, (size_t)NBK * 4 + (size_t)N_GRAPHS * 2 * 4, stream);

    scatter_kernel<<<SCAT_BLOCKS + GB + 32, 256, 0, stream>>>(
        src, dst, x, cursor, edge8,
        batch, gstart, emb, W1l, W1r, W2l, W2r, embW1l, embW1r, w2frag, p8);
    csr_kernel<<<NBK, 256, 0, stream>>>(edge8, cursor, rowst, deg, col,
                                        embW1l, embW1r, w1frag);
    sage1_kernel<<<NBK * 2, 256, 0, stream>>>(
        x, deg, edge8, cursor, w1frag, w2frag, b1, p8, q16);
    sage2_kernel<<<N_NODES / (4 * S2_NPW), 256, 0, stream>>>(
        p8, q16, rowst, deg, col, b2, Wout, batch, gsum);
    finalize_kernel<<<(N_GRAPHS + 255) / 256, 256, 0, stream>>>(gsum, gstart, bout, out);
}